// Round 3
// baseline (2848.899 us; speedup 1.0000x reference)
//
#include <hip/hip_runtime.h>
#include <math.h>

// ---------------------------------------------------------------------------
// CNN-LSTM video predictor, fp32, round 3: occupancy-fixed convs (NB packing,
// small per-thread tiles, 512-1024 block grids). LSTM chain as round 2.
// ---------------------------------------------------------------------------

__device__ __forceinline__ float sig_(float x) { return 1.f / (1.f + expf(-x)); }

// LSTM column permutation: block b (of 64) owns j in [8b, 8b+8); within-block
// col i = g*8 + jl maps to original gate row g*512 + 8b + jl. c = 32b + i.
__device__ __forceinline__ int orig_row(int c) {
    return ((c >> 3) & 3) * 512 + (c >> 5) * 8 + (c & 7);
}

// ======================= encoder conv (s2, k4, p1, relu) ====================
// Block: NB images x COB out-channels x spatial tile. 256 threads =
// (COB/COT) channel-groups x SPT spatial threads; each thread: COT x OWT outs.
template<int CI, int HI, int WI, int CO, int COB, int COT, int OWT, int CICH, int NB>
__global__ __launch_bounds__(256)
void conv_enc(const float* __restrict__ x, const float* __restrict__ w,
              const float* __restrict__ bias, float* __restrict__ y) {
    constexpr int HO = HI / 2, WO = WI / 2;
    constexpr int GROUPS = COB / COT, SPT = 256 / GROUPS;
    constexpr int TILES = (NB * HO * WO) / (SPT * OWT);
    constexpr int COBS = CO / COB;
    int bid = blockIdx.x;
    int tile = bid % TILES; bid /= TILES;
    int cob = bid % COBS;   int n0 = (bid / COBS) * NB;
    int tid = threadIdx.x;
    int cog = tid / SPT, sp = tid % SPT;
    int sidx = (tile * SPT + sp) * OWT;
    int nb = sidx / (HO * WO); int rem = sidx % (HO * WO);
    int oh = rem / WO, ow0 = rem % WO;
    int n = n0 + nb;

    __shared__ float wl[COB * CICH * 16];
    float acc[COT][OWT];
#pragma unroll
    for (int a = 0; a < COT; ++a)
#pragma unroll
        for (int q = 0; q < OWT; ++q) acc[a][q] = 0.f;

    const float* xn = x + (long)n * CI * HI * WI;
    for (int cc = 0; cc < CI; cc += CICH) {
        __syncthreads();
        for (int i = tid; i < COB * CICH * 16; i += 256) {
            int k = i & 15, ci = (i >> 4) % CICH, co = i / (16 * CICH);
            wl[i] = w[((cob * COB + co) * CI + cc + ci) * 16 + k];
        }
        __syncthreads();
        for (int ci = 0; ci < CICH; ++ci) {
            const float* xc = xn + (long)(cc + ci) * HI * WI;
            float patch[4][2 * OWT + 2];
#pragma unroll
            for (int r = 0; r < 4; ++r) {
                int ih = 2 * oh + r - 1;
                bool rv = (ih >= 0) && (ih < HI);
#pragma unroll
                for (int cx = 0; cx < 2 * OWT + 2; ++cx) {
                    int iw = 2 * ow0 + cx - 1;
                    patch[r][cx] = (rv && iw >= 0 && iw < WI) ? xc[ih * WI + iw] : 0.f;
                }
            }
#pragma unroll
            for (int ct = 0; ct < COT; ++ct) {
                const float* wp = &wl[((cog * COT + ct) * CICH + ci) * 16];
                float wr[16];
#pragma unroll
                for (int k = 0; k < 16; ++k) wr[k] = wp[k];
#pragma unroll
                for (int q = 0; q < OWT; ++q) {
                    float s = acc[ct][q];
#pragma unroll
                    for (int kh = 0; kh < 4; ++kh)
#pragma unroll
                        for (int kw = 0; kw < 4; ++kw)
                            s += patch[kh][2 * q + kw] * wr[kh * 4 + kw];
                    acc[ct][q] = s;
                }
            }
        }
    }
    for (int ct = 0; ct < COT; ++ct) {
        int co = cob * COB + cog * COT + ct;
        float bv = bias[co];
        for (int q = 0; q < OWT; ++q) {
            float v = fmaxf(acc[ct][q] + bv, 0.f);
            y[(((long)n * CO + co) * HO + oh) * WO + ow0 + q] = v;
        }
    }
}

// ================= decoder transposed conv (s2, k4, p1-equiv) ===============
// Quad (2x2 outputs) per input position. NB images per block. ACT: 0 relu,
// 1 sigmoid.
template<int CI, int HI, int WI, int CO, int COB, int COT, int OQT, int CICH, int NB, int ACT>
__global__ __launch_bounds__(256)
void convt_dec(const float* __restrict__ x, const float* __restrict__ w,
               const float* __restrict__ bias, float* __restrict__ y) {
    constexpr int HO = HI * 2, WO = WI * 2;
    constexpr int GROUPS = COB / COT, SPT = 256 / GROUPS;
    constexpr int TILES = (NB * HI * WI) / (SPT * OQT);
    constexpr int COBS = CO / COB;
    int bid = blockIdx.x;
    int tile = bid % TILES; bid /= TILES;
    int cob = bid % COBS;   int n0 = (bid / COBS) * NB;
    int tid = threadIdx.x;
    int cog = tid / SPT, sp = tid % SPT;
    int qidx = (tile * SPT + sp) * OQT;
    int nb = qidx / (HI * WI); int rem = qidx % (HI * WI);
    int qy = rem / WI, qx0 = rem % WI;
    int n = n0 + nb;

    __shared__ float wl[COB * CICH * 16];
    float acc[COT][OQT * 4];
#pragma unroll
    for (int a = 0; a < COT; ++a)
#pragma unroll
        for (int q = 0; q < OQT * 4; ++q) acc[a][q] = 0.f;

    const float* xn = x + (long)n * CI * HI * WI;
    for (int cc = 0; cc < CI; cc += CICH) {
        __syncthreads();
        for (int i = tid; i < COB * CICH * 16; i += 256) {
            int k = i & 15, ci = (i >> 4) % CICH, co = i / (16 * CICH);
            wl[i] = w[((cob * COB + co) * CI + cc + ci) * 16 + k];
        }
        __syncthreads();
        for (int ci = 0; ci < CICH; ++ci) {
            const float* xc = xn + (long)(cc + ci) * HI * WI;
            float patch[3][OQT + 2];
#pragma unroll
            for (int r = 0; r < 3; ++r) {
                int ih = qy + r - 1;
                bool rv = (ih >= 0) && (ih < HI);
#pragma unroll
                for (int cx = 0; cx < OQT + 2; ++cx) {
                    int iw = qx0 + cx - 1;
                    patch[r][cx] = (rv && iw >= 0 && iw < WI) ? xc[ih * WI + iw] : 0.f;
                }
            }
#pragma unroll
            for (int ct = 0; ct < COT; ++ct) {
                const float* wp = &wl[((cog * COT + ct) * CICH + ci) * 16];
                float wr[16];
#pragma unroll
                for (int k = 0; k < 16; ++k) wr[k] = wp[k];
#pragma unroll
                for (int q = 0; q < OQT; ++q)
#pragma unroll
                    for (int p = 0; p < 2; ++p)
#pragma unroll
                        for (int qq = 0; qq < 2; ++qq) {
                            float s = acc[ct][q * 4 + p * 2 + qq];
#pragma unroll
                            for (int dh = 0; dh < 2; ++dh)
#pragma unroll
                                for (int dw = 0; dw < 2; ++dw)
                                    s += patch[p + dh][q + qq + dw] * wr[(p + 2 * dh) * 4 + (qq + 2 * dw)];
                            acc[ct][q * 4 + p * 2 + qq] = s;
                        }
            }
        }
    }
    for (int ct = 0; ct < COT; ++ct) {
        int co = cob * COB + cog * COT + ct;
        float bv = bias[co];
        for (int q = 0; q < OQT; ++q)
            for (int p = 0; p < 2; ++p)
                for (int qq = 0; qq < 2; ++qq) {
                    float v = acc[ct][q * 4 + p * 2 + qq] + bv;
                    v = (ACT == 1) ? sig_(v) : fmaxf(v, 0.f);
                    y[(((long)n * CO + co) * HO + 2 * qy + p) * WO + 2 * (qx0 + q) + qq] = v;
                }
    }
}

// ====================== generic transpose: out[c*R+r] = in[r*C+c] ===========
__global__ void transp(const float* __restrict__ in, float* __restrict__ out,
                       int R, int C) {
    long idx = (long)blockIdx.x * 256 + threadIdx.x;
    if (idx >= (long)R * C) return;
    int r = (int)(idx % R), c = (int)(idx / R);
    out[idx] = in[(long)r * C + c];
}

// permuted transpose of wih: out[m*2048 + c] = wih[orig(c)*128 + m]
__global__ void perm_wih(const float* __restrict__ wih, float* __restrict__ out) {
    int idx = blockIdx.x * 256 + threadIdx.x;  // < 262144
    int c = idx & 2047, m = idx >> 11;
    out[idx] = wih[orig_row(c) * 128 + m];
}

// permute+pack whh: out float4[k4*2048 + c] = whh[orig(c)][4k4..4k4+3]
__global__ void pack_whh(const float* __restrict__ whh, float4* __restrict__ out) {
    int idx = blockIdx.x * 256 + threadIdx.x;  // < 262144
    int c = idx & 2047, k4 = idx >> 11;
    const float4* src = (const float4*)(whh + orig_row(c) * 512);
    out[idx] = src[k4];
}

// merged decoder recurrent weights: Wcomb[k][c] = whh_d[orig(c)][k]
//   + sum_m fc_w[m][k] * wih_d[orig(c)][m] ; packed-f4 layout
__global__ __launch_bounds__(256)
void merge_dc(const float* __restrict__ wih_d, const float* __restrict__ fc_w,
              const float* __restrict__ whh_d, float* __restrict__ out) {
    int cb = (blockIdx.x >> 3) * 64, kb = (blockIdx.x & 7) * 64;
    int tid = threadIdx.x;
    int cgl = (tid & 15) * 4, kgl = (tid >> 4) * 4;
    __shared__ float At[64][65];
    __shared__ float Bt[64][65];
    float acc[4][4] = {};
    for (int mc = 0; mc < 128; mc += 64) {
        __syncthreads();
        for (int i = tid; i < 4096; i += 256) {
            int cl = i >> 6, m = i & 63;
            At[cl][m] = wih_d[orig_row(cb + cl) * 128 + mc + m];
            Bt[cl][m] = fc_w[(mc + cl) * 512 + kb + m];
        }
        __syncthreads();
        for (int m = 0; m < 64; ++m) {
            float a[4], b[4];
#pragma unroll
            for (int i = 0; i < 4; ++i) { a[i] = At[cgl + i][m]; b[i] = Bt[m][kgl + i]; }
#pragma unroll
            for (int i = 0; i < 4; ++i)
#pragma unroll
                for (int j = 0; j < 4; ++j) acc[i][j] += a[i] * b[j];
        }
    }
    for (int i = 0; i < 4; ++i) {
        int c = cb + cgl + i; int orow = orig_row(c);
        for (int j = 0; j < 4; ++j) {
            int k = kb + kgl + j;
            out[((k >> 2) * 2048 + c) * 4 + (k & 3)] = acc[i][j] + whh_d[orow * 512 + k];
        }
    }
}

// decoder steady-state bias: bih+bhh + fc_b @ wih_d^T (permuted index)
__global__ void biasdc_k(const float* __restrict__ bih, const float* __restrict__ bhh,
                         const float* __restrict__ wih_d, const float* __restrict__ fc_b,
                         float* __restrict__ out) {
    int c = blockIdx.x * 256 + threadIdx.x;
    if (c >= 2048) return;
    int orow = orig_row(c);
    float s = bih[orow] + bhh[orow];
    for (int m = 0; m < 128; ++m) s += fc_b[m] * wih_d[orow * 128 + m];
    out[c] = s;
}

// x-projection: out[r][c] = sum_m z[r][m]*wihP[m][c] + bih[orig]+bhh[orig]
__global__ __launch_bounds__(512)
void gx_kernel(const float* __restrict__ z, int zrstride,
               const float* __restrict__ wihP, const float* __restrict__ bih,
               const float* __restrict__ bhh, float* __restrict__ out) {
    int rg = blockIdx.x >> 2, cch = blockIdx.x & 3;
    int tid = threadIdx.x;
    __shared__ float zl[16 * 128];
    for (int i = tid; i < 2048; i += 512)
        zl[i] = z[(long)(rg * 16 + (i >> 7)) * zrstride + (i & 127)];
    __syncthreads();
    int c = cch * 512 + tid;
    int orow = orig_row(c);
    float bsum = bih[orow] + bhh[orow];
    float acc[16];
#pragma unroll
    for (int r = 0; r < 16; ++r) acc[r] = bsum;
    for (int m = 0; m < 128; ++m) {
        float wv = wihP[m * 2048 + c];
#pragma unroll
        for (int r = 0; r < 16; ++r) acc[r] += zl[r * 128 + m] * wv;
    }
    for (int r = 0; r < 16; ++r) out[(long)(rg * 16 + r) * 2048 + c] = acc[r];
}

// one LSTM step: 64 blocks x 512 threads
__global__ __launch_bounds__(512)
void lstm_step(const float4* __restrict__ wh4, const float* __restrict__ gadd,
               int gstride, const float* __restrict__ h_in, float* __restrict__ h_out,
               float* __restrict__ cst, float* __restrict__ hall) {
    __shared__ float hs[8192];
    __shared__ float gb[16][32];
    int tid = threadIdx.x;
    float4* hs4 = (float4*)hs;
    const float4* hi4 = (const float4*)h_in;
#pragma unroll
    for (int i = 0; i < 4; ++i) hs4[tid + 512 * i] = hi4[tid + 512 * i];
    __syncthreads();
    int col = tid & 31, n = tid >> 5;
    int cg = blockIdx.x * 32 + col;
    float acc = gadd[n * gstride + cg];
    const float4* wp = wh4 + cg;
    const float4* hv = (const float4*)(hs + n * 512);
#pragma unroll 8
    for (int k4 = 0; k4 < 128; ++k4) {
        float4 wv = wp[(long)k4 * 2048];
        float4 h4 = hv[k4];
        acc += wv.x * h4.x + wv.y * h4.y + wv.z * h4.z + wv.w * h4.w;
    }
    gb[n][col] = acc;
    __syncthreads();
    if (col < 8) {
        int j = blockIdx.x * 8 + col;
        float gi = sig_(gb[n][col]);
        float gf = sig_(gb[n][col + 8]);
        float gg = tanhf(gb[n][col + 16]);
        float go = sig_(gb[n][col + 24]);
        int idx = n * 512 + j;
        float cv = gf * cst[idx] + gi * gg;
        cst[idx] = cv;
        float hvv = go * tanhf(cv);
        h_out[idx] = hvv;
        if (hall) hall[idx] = hvv;
    }
}

// fcmu partial GEMM: 16 row-groups x 8 k-slices
__global__ __launch_bounds__(512)
void fcmu_part(const float* __restrict__ x, const float* __restrict__ wP,
               float* __restrict__ part) {
    int rg = blockIdx.x >> 3, ks = blockIdx.x & 7;
    int tid = threadIdx.x;
    __shared__ float xl[16 * 512];
    for (int i = tid; i < 8192; i += 512)
        xl[i] = x[(long)(rg * 16 + (i >> 9)) * 4096 + ks * 512 + (i & 511)];
    __syncthreads();
    int j = tid & 127, rq = tid >> 7;
    float acc[4] = {0, 0, 0, 0};
    for (int k = 0; k < 512; ++k) {
        float wv = wP[(ks * 512 + k) * 128 + j];
#pragma unroll
        for (int i = 0; i < 4; ++i) acc[i] += xl[(rq + 4 * i) * 512 + k] * wv;
    }
    for (int i = 0; i < 4; ++i)
        part[((long)ks * 256 + rg * 16 + rq + 4 * i) * 128 + j] = acc[i];
}

__global__ void fcmu_red(const float* __restrict__ part, const float* __restrict__ b,
                         float* __restrict__ z) {
    int idx = blockIdx.x * 256 + threadIdx.x;  // 32768
    float s = b[idx & 127];
    for (int k = 0; k < 8; ++k) s += part[k * 32768 + idx];
    z[idx] = s;
}

// zs = Hall[t] @ fc_w^T + fc_b (one block per t)
__global__ __launch_bounds__(512)
void zs_k(const float* __restrict__ hall, const float* __restrict__ fcP,
          const float* __restrict__ fcb, float* __restrict__ zs) {
    int t = blockIdx.x;
    int tid = threadIdx.x;
    __shared__ float hs[8192];
    const float* h = hall + t * 8192;
    for (int i = tid; i < 8192; i += 512) hs[i] = h[i];
    __syncthreads();
    int j = tid & 127, ng = tid >> 7;
    float acc[4] = {0, 0, 0, 0};
    for (int k = 0; k < 512; ++k) {
        float wv = fcP[k * 128 + j];
#pragma unroll
        for (int i = 0; i < 4; ++i) acc[i] += hs[(ng + 4 * i) * 512 + k] * wv;
    }
    float bv = fcb[j];
    for (int i = 0; i < 4; ++i)
        zs[((ng + 4 * i) * 16 + t) * 128 + j] = acc[i] + bv;
}

// dfc: out[r][j] = relu(sum_m zs[r][m]*dfcP[m][j] + b[j])
__global__ __launch_bounds__(512)
void dfc_k(const float* __restrict__ zs, const float* __restrict__ dP,
           const float* __restrict__ db, float* __restrict__ out) {
    int rg = blockIdx.x >> 3, jc = blockIdx.x & 7;
    int tid = threadIdx.x;
    __shared__ float zl[16 * 128];
    for (int i = tid; i < 2048; i += 512) zl[i] = zs[(long)rg * 2048 + i];
    __syncthreads();
    int j = jc * 512 + tid;
    float acc[16];
#pragma unroll
    for (int r = 0; r < 16; ++r) acc[r] = 0.f;
    for (int m = 0; m < 128; ++m) {
        float wv = dP[(long)m * 4096 + j];
#pragma unroll
        for (int r = 0; r < 16; ++r) acc[r] += zl[r * 128 + m] * wv;
    }
    float bv = db[j];
    for (int r = 0; r < 16; ++r)
        out[(long)(rg * 16 + r) * 4096 + j] = fmaxf(acc[r] + bv, 0.f);
}

extern "C" void kernel_launch(void* const* d_in, const int* in_sizes, int n_in,
                              void* d_out, int out_size, void* d_ws, size_t ws_size,
                              hipStream_t stream) {
    (void)in_sizes; (void)n_in; (void)out_size; (void)ws_size;
    const float* video  = (const float*)d_in[0];
    const float* ec1_w  = (const float*)d_in[2];  const float* ec1_b = (const float*)d_in[3];
    const float* ec2_w  = (const float*)d_in[4];  const float* ec2_b = (const float*)d_in[5];
    const float* ec3_w  = (const float*)d_in[6];  const float* ec3_b = (const float*)d_in[7];
    const float* ec4_w  = (const float*)d_in[8];  const float* ec4_b = (const float*)d_in[9];
    const float* fcmu_w = (const float*)d_in[10]; const float* fcmu_b = (const float*)d_in[11];
    const float* dfc_w  = (const float*)d_in[12]; const float* dfc_b = (const float*)d_in[13];
    const float* dt1_w  = (const float*)d_in[14]; const float* dt1_b = (const float*)d_in[15];
    const float* dt2_w  = (const float*)d_in[16]; const float* dt2_b = (const float*)d_in[17];
    const float* dt3_w  = (const float*)d_in[18]; const float* dt3_b = (const float*)d_in[19];
    const float* dt4_w  = (const float*)d_in[20]; const float* dt4_b = (const float*)d_in[21];
    const float* wih_e  = (const float*)d_in[22]; const float* whh_e = (const float*)d_in[23];
    const float* bih_e  = (const float*)d_in[24]; const float* bhh_e = (const float*)d_in[25];
    const float* wih_d  = (const float*)d_in[26]; const float* whh_d = (const float*)d_in[27];
    const float* bih_d  = (const float*)d_in[28]; const float* bhh_d = (const float*)d_in[29];
    const float* fc_w   = (const float*)d_in[30]; const float* fc_b  = (const float*)d_in[31];

    float* ws = (float*)d_ws;
    float* A1 = ws;                 // 8,388,608 floats
    float* A2 = ws + 8388608;       // 4,194,304
    float* A3 = ws + 12582912;      // 2,097,152
    float* A4 = ws + 14680064;      // 1,048,576
    float* Z      = A3;             // 32768 (A3 dead after conv4)
    float* WH4_E  = A1;             // buffers below live in A1 (dead after conv2)
    float* WH4_D0 = A1 + 1048576;
    float* WH4_DC = A1 + 2097152;
    float* GX_E   = A1 + 3145728;
    float* GX_D0  = A1 + 3670016;
    float* WIHP_E = A1 + 3702784;
    float* WIHP_D = A1 + 3964928;
    float* FCP    = A1 + 4227072;
    float* FCMUP  = A1 + 4292608;
    float* DFCP   = A1 + 4816896;
    float* BIASDC = A1 + 5341184;
    float* ZPART  = A1 + 5343232;
    float* HALL   = A1 + 5605376;
    float* HA     = A1 + 5736448;
    float* HB     = A1 + 5744640;
    float* CB     = A1 + 5752832;
    float* ZS     = A1 + 5761024;

    // ------------- encoder CNN -------------
    // grids: 1024 / 1024 / 1024 / 512 blocks (>= 2 blocks/CU)
    conv_enc<3, 64, 64, 32, 32, 8, 4, 3, 1><<<1024, 256, 0, stream>>>(video, ec1_w, ec1_b, A1);
    conv_enc<32, 32, 32, 64, 64, 8, 2, 4, 1><<<1024, 256, 0, stream>>>(A1, ec2_w, ec2_b, A2);
    conv_enc<64, 16, 16, 128, 32, 8, 1, 4, 1><<<1024, 256, 0, stream>>>(A2, ec3_w, ec3_b, A3);
    conv_enc<128, 8, 8, 256, 64, 8, 1, 4, 2><<<512, 256, 0, stream>>>(A3, ec4_w, ec4_b, A4);

    // ------------- weight prep (A1 free after conv2) -------------
    transp<<<2048, 256, 0, stream>>>(fcmu_w, FCMUP, 128, 4096);
    transp<<<256, 256, 0, stream>>>(fc_w, FCP, 128, 512);
    transp<<<2048, 256, 0, stream>>>(dfc_w, DFCP, 4096, 128);
    perm_wih<<<1024, 256, 0, stream>>>(wih_e, WIHP_E);
    perm_wih<<<1024, 256, 0, stream>>>(wih_d, WIHP_D);
    pack_whh<<<1024, 256, 0, stream>>>(whh_e, (float4*)WH4_E);
    pack_whh<<<1024, 256, 0, stream>>>(whh_d, (float4*)WH4_D0);
    merge_dc<<<256, 256, 0, stream>>>(wih_d, fc_w, whh_d, WH4_DC);
    biasdc_k<<<8, 256, 0, stream>>>(bih_d, bhh_d, wih_d, fc_b, BIASDC);

    // ------------- fcmu: A4 [256,4096] -> Z [256,128] -------------
    fcmu_part<<<128, 512, 0, stream>>>(A4, FCMUP, ZPART);
    fcmu_red<<<128, 256, 0, stream>>>(ZPART, fcmu_b, Z);

    // ------------- x-projections -------------
    gx_kernel<<<64, 512, 0, stream>>>(Z, 128, WIHP_E, bih_e, bhh_e, GX_E);
    gx_kernel<<<4, 512, 0, stream>>>(Z + 15 * 128, 2048, WIHP_D, bih_d, bhh_d, GX_D0);

    // ------------- LSTM chains -------------
    hipMemsetAsync(HA, 0, 3 * 8192 * sizeof(float), stream);  // HA, HB, CB
    float* hin = HA; float* hout = HB;
    for (int t = 0; t < 16; ++t) {
        lstm_step<<<64, 512, 0, stream>>>((const float4*)WH4_E, GX_E + t * 2048, 32768,
                                          hin, hout, CB, (float*)nullptr);
        float* tmp = hin; hin = hout; hout = tmp;
    }
    lstm_step<<<64, 512, 0, stream>>>((const float4*)WH4_D0, GX_D0, 2048,
                                      hin, hout, CB, HALL);
    { float* tmp = hin; hin = hout; hout = tmp; }
    for (int t = 1; t < 16; ++t) {
        lstm_step<<<64, 512, 0, stream>>>((const float4*)WH4_DC, BIASDC, 0,
                                          hin, hout, CB, HALL + t * 8192);
        float* tmp = hin; hin = hout; hout = tmp;
    }
    zs_k<<<16, 512, 0, stream>>>(HALL, FCP, fc_b, ZS);

    // ------------- decoder CNN -------------
    dfc_k<<<128, 512, 0, stream>>>(ZS, DFCP, dfc_b, A4);
    // grids: 512 / 512 / 1024 / 1024
    convt_dec<256, 4, 4, 128, 64, 4, 1, 4, 1, 0><<<512, 256, 0, stream>>>(A4, dt1_w, dt1_b, A3);
    convt_dec<128, 8, 8, 64, 32, 8, 1, 4, 1, 0><<<512, 256, 0, stream>>>(A3, dt2_w, dt2_b, A2);
    convt_dec<64, 16, 16, 32, 32, 8, 1, 4, 1, 0><<<1024, 256, 0, stream>>>(A2, dt3_w, dt3_b, A1);
    convt_dec<32, 32, 32, 3, 3, 3, 1, 4, 1, 1><<<1024, 256, 0, stream>>>(A1, dt4_w, dt4_b, (float*)d_out);
}

// Round 4
// 1299.137 us; speedup vs baseline: 2.1929x; 2.1929x over previous
//
#include <hip/hip_runtime.h>
#include <math.h>

// ---------------------------------------------------------------------------
// CNN-LSTM video predictor, fp32, round 4: channels-last implicit-GEMM convs
// (one tiled-GEMM core for all 8 layers), LSTM chain as round 2.
// Layouts: activations NHWC; conv weights prepped to [tap][ci][co];
// convT done as 4 parity sub-GEMMs (K = CI*4 each).
// ---------------------------------------------------------------------------

__device__ __forceinline__ float sig_(float x) { return 1.f / (1.f + expf(-x)); }

__device__ __forceinline__ int orig_row(int c) {
    return ((c >> 3) & 3) * 512 + (c >> 5) * 8 + (c & 7);
}

// =============== encoder conv as implicit GEMM (s2, k4, p1, relu) ==========
// X: NHWC [256][HI][WI][CI]; Wt: [16][CI][CO]; y: NHWC [256][HO][WO][CO]
template<int CI, int HI, int WI, int CO, int BM, int BN, int TM, int TN, int KC>
__global__ __launch_bounds__(256)
void conv_gemm(const float* __restrict__ X, const float* __restrict__ Wt,
               const float* __restrict__ bias, float* __restrict__ y) {
    constexpr int HO = HI / 2, WO = WI / 2;
    constexpr int HWO = HO * WO;
    constexpr int MTOT = 256 * HWO;
    constexpr int MT = MTOT / BM;
    constexpr int MG = BM / TM, NG = BN / TN;
    static_assert(MG * NG == 256, "bad tile");
    __shared__ float Xs[KC][BM + 4];
    __shared__ float Ws[KC][BN + 4];
    int bid = blockIdx.x;
    int mt = bid % MT, nt = bid / MT;
    int m0 = mt * BM, n0 = nt * BN;
    int tid = threadIdx.x;
    int tmg = tid % MG, tng = tid / MG;
    float acc[TM][TN] = {};

    for (int tap = 0; tap < 16; ++tap) {
        int kh = tap >> 2, kw = tap & 3;
        for (int cc = 0; cc < CI; cc += KC) {
            __syncthreads();
            for (int item = tid; item < BM * (KC / 4); item += 256) {
                int row = item / (KC / 4), kq = item % (KC / 4);
                int m = m0 + row;
                int n_ = m / HWO, rem = m % HWO;
                int oh = rem / WO, ow = rem % WO;
                int ih = 2 * oh + kh - 1, iw = 2 * ow + kw - 1;
                float4 v = {0.f, 0.f, 0.f, 0.f};
                if (ih >= 0 && ih < HI && iw >= 0 && iw < WI)
                    v = *(const float4*)(X + (((long)n_ * HI + ih) * WI + iw) * CI + cc + kq * 4);
                Xs[kq * 4 + 0][row] = v.x; Xs[kq * 4 + 1][row] = v.y;
                Xs[kq * 4 + 2][row] = v.z; Xs[kq * 4 + 3][row] = v.w;
            }
            for (int item = tid; item < KC * (BN / 4); item += 256) {
                int kr = item / (BN / 4), jq = item % (BN / 4);
                *(float4*)&Ws[kr][jq * 4] =
                    *(const float4*)(Wt + ((long)tap * CI + cc + kr) * CO + n0 + jq * 4);
            }
            __syncthreads();
#pragma unroll
            for (int k = 0; k < KC; ++k) {
                float a[TM], b[TN];
#pragma unroll
                for (int i = 0; i < TM; ++i) a[i] = Xs[k][tmg * TM + i];
#pragma unroll
                for (int j = 0; j < TN; ++j) b[j] = Ws[k][tng * TN + j];
#pragma unroll
                for (int i = 0; i < TM; ++i)
#pragma unroll
                    for (int j = 0; j < TN; ++j) acc[i][j] += a[i] * b[j];
            }
        }
    }
#pragma unroll
    for (int i = 0; i < TM; ++i) {
        long m = m0 + tmg * TM + i;
#pragma unroll
        for (int j = 0; j < TN; ++j) {
            int co = n0 + tng * TN + j;
            y[m * CO + co] = fmaxf(acc[i][j] + bias[co], 0.f);
        }
    }
}

// =============== transposed conv as parity implicit GEMM ====================
// per parity (p,q): out[n,2y+p,2x+q,co] = sum_{dh,dw,ci} X[n,y+p+dh-1,x+q+dw-1,ci]
//                                         * w[co,ci,p+2dh,q+2dw]
// ACT: 0 relu, 1 sigmoid. NCHW: write d_out layout [n][COR][HO][WO].
template<int CI, int HI, int WI, int CO, int COR, int BM, int BN, int TM, int TN,
         int KC, int ACT, int NCHW>
__global__ __launch_bounds__(256)
void convt_gemm(const float* __restrict__ X, const float* __restrict__ Wt,
                const float* __restrict__ bias, float* __restrict__ y) {
    constexpr int HO = HI * 2, WO = WI * 2;
    constexpr int HWI = HI * WI;
    constexpr int MTOT = 256 * HWI;
    constexpr int MT = MTOT / BM;
    constexpr int NT = CO / BN;
    constexpr int MG = BM / TM, NG = BN / TN;
    static_assert(MG * NG == 256, "bad tile");
    __shared__ float Xs[KC][BM + 4];
    __shared__ float Ws[KC][BN + 4];
    int bid = blockIdx.x;
    int mt = bid % MT; bid /= MT;
    int nt = bid % NT; int par = bid / NT;
    int p = par >> 1, q = par & 1;
    int m0 = mt * BM, n0 = nt * BN;
    int tid = threadIdx.x;
    int tmg = tid % MG, tng = tid / MG;
    float acc[TM][TN] = {};

    for (int t4 = 0; t4 < 4; ++t4) {
        int dh = t4 >> 1, dw = t4 & 1;
        int tap = (p + 2 * dh) * 4 + (q + 2 * dw);
        for (int cc = 0; cc < CI; cc += KC) {
            __syncthreads();
            for (int item = tid; item < BM * (KC / 4); item += 256) {
                int row = item / (KC / 4), kq = item % (KC / 4);
                int m = m0 + row;
                int n_ = m / HWI, rem = m % HWI;
                int yy = rem / WI, xx = rem % WI;
                int ih = yy + p + dh - 1, iw = xx + q + dw - 1;
                float4 v = {0.f, 0.f, 0.f, 0.f};
                if (ih >= 0 && ih < HI && iw >= 0 && iw < WI)
                    v = *(const float4*)(X + (((long)n_ * HI + ih) * WI + iw) * CI + cc + kq * 4);
                Xs[kq * 4 + 0][row] = v.x; Xs[kq * 4 + 1][row] = v.y;
                Xs[kq * 4 + 2][row] = v.z; Xs[kq * 4 + 3][row] = v.w;
            }
            for (int item = tid; item < KC * (BN / 4); item += 256) {
                int kr = item / (BN / 4), jq = item % (BN / 4);
                *(float4*)&Ws[kr][jq * 4] =
                    *(const float4*)(Wt + ((long)tap * CI + cc + kr) * CO + n0 + jq * 4);
            }
            __syncthreads();
#pragma unroll
            for (int k = 0; k < KC; ++k) {
                float a[TM], b[TN];
#pragma unroll
                for (int i = 0; i < TM; ++i) a[i] = Xs[k][tmg * TM + i];
#pragma unroll
                for (int j = 0; j < TN; ++j) b[j] = Ws[k][tng * TN + j];
#pragma unroll
                for (int i = 0; i < TM; ++i)
#pragma unroll
                    for (int j = 0; j < TN; ++j) acc[i][j] += a[i] * b[j];
            }
        }
    }
#pragma unroll
    for (int i = 0; i < TM; ++i) {
        int m = m0 + tmg * TM + i;
        int n_ = m / HWI, rem = m % HWI;
        int oh = 2 * (rem / WI) + p, ow = 2 * (rem % WI) + q;
#pragma unroll
        for (int j = 0; j < TN; ++j) {
            int co = n0 + tng * TN + j;
            float v = acc[i][j] + bias[co];
            v = (ACT == 1) ? sig_(v) : fmaxf(v, 0.f);
            if (NCHW) {
                if (co < COR)
                    y[(((long)n_ * COR + co) * HO + oh) * WO + ow] = v;
            } else {
                y[(((long)n_ * HO + oh) * WO + ow) * CO + co] = v;
            }
        }
    }
}

// ========================= layout / weight prep =============================
// conv weight OIHW -> [tap][ci][co] with optional zero padding of ci/co
template<int CI_S, int CI_P, int CO_S, int CO_P>
__global__ void perm_w(const float* __restrict__ w, float* __restrict__ out) {
    int idx = blockIdx.x * 256 + threadIdx.x;
    constexpr int TOT = 16 * CI_P * CO_P;
    if (idx >= TOT) return;
    int co = idx % CO_P; int ci = (idx / CO_P) % CI_P; int t = idx / (CO_P * CI_P);
    out[idx] = (ci < CI_S && co < CO_S) ? w[((long)co * CI_S + ci) * 16 + t] : 0.f;
}

// video NCHW -> NHWC padded to 4 channels
__global__ void to_nhwc4(const float* __restrict__ v, float* __restrict__ out) {
    int idx = blockIdx.x * 256 + threadIdx.x;  // 4,194,304
    int c = idx & 3; int w = (idx >> 2) & 63; int h = (idx >> 8) & 63; int n = idx >> 14;
    out[idx] = (c < 3) ? v[(((long)n * 3 + c) * 64 + h) * 64 + w] : 0.f;
}

// fcmu_w [128][4096 chw] -> FCMUP[k_hwc][j]
__global__ void perm_fcmu(const float* __restrict__ w, float* __restrict__ out) {
    int idx = blockIdx.x * 256 + threadIdx.x;  // 524288
    int j = idx & 127; int k = idx >> 7;       // k = (h*4+w)*256 + c
    out[idx] = w[(long)j * 4096 + (k & 255) * 16 + (k >> 8)];
}

// dfc_w [4096 chw][128] -> DFCP[m][j_hwc]; dfc_b -> DFCB[j_hwc]
__global__ void perm_dfc(const float* __restrict__ w, const float* __restrict__ b,
                         float* __restrict__ outw, float* __restrict__ outb) {
    int idx = blockIdx.x * 256 + threadIdx.x;  // 524288
    int j = idx & 4095; int m = idx >> 12;
    int jc = (j & 255) * 16 + (j >> 8);
    outw[idx] = w[(long)jc * 128 + m];
    if (idx < 4096) outb[idx] = b[(idx & 255) * 16 + (idx >> 8)];
}

__global__ void pad_b16(const float* __restrict__ b, float* __restrict__ out) {
    int i = threadIdx.x;
    if (i < 16) out[i] = (i < 3) ? b[i] : 0.f;
}

__global__ void transp(const float* __restrict__ in, float* __restrict__ out,
                       int R, int C) {
    long idx = (long)blockIdx.x * 256 + threadIdx.x;
    if (idx >= (long)R * C) return;
    int r = (int)(idx % R), c = (int)(idx / R);
    out[idx] = in[(long)r * C + c];
}

__global__ void perm_wih(const float* __restrict__ wih, float* __restrict__ out) {
    int idx = blockIdx.x * 256 + threadIdx.x;  // < 262144
    int c = idx & 2047, m = idx >> 11;
    out[idx] = wih[orig_row(c) * 128 + m];
}

__global__ void pack_whh(const float* __restrict__ whh, float4* __restrict__ out) {
    int idx = blockIdx.x * 256 + threadIdx.x;  // < 262144
    int c = idx & 2047, k4 = idx >> 11;
    const float4* src = (const float4*)(whh + orig_row(c) * 512);
    out[idx] = src[k4];
}

__global__ __launch_bounds__(256)
void merge_dc(const float* __restrict__ wih_d, const float* __restrict__ fc_w,
              const float* __restrict__ whh_d, float* __restrict__ out) {
    int cb = (blockIdx.x >> 3) * 64, kb = (blockIdx.x & 7) * 64;
    int tid = threadIdx.x;
    int cgl = (tid & 15) * 4, kgl = (tid >> 4) * 4;
    __shared__ float At[64][65];
    __shared__ float Bt[64][65];
    float acc[4][4] = {};
    for (int mc = 0; mc < 128; mc += 64) {
        __syncthreads();
        for (int i = tid; i < 4096; i += 256) {
            int cl = i >> 6, m = i & 63;
            At[cl][m] = wih_d[orig_row(cb + cl) * 128 + mc + m];
            Bt[cl][m] = fc_w[(mc + cl) * 512 + kb + m];
        }
        __syncthreads();
        for (int m = 0; m < 64; ++m) {
            float a[4], b[4];
#pragma unroll
            for (int i = 0; i < 4; ++i) { a[i] = At[cgl + i][m]; b[i] = Bt[m][kgl + i]; }
#pragma unroll
            for (int i = 0; i < 4; ++i)
#pragma unroll
                for (int j = 0; j < 4; ++j) acc[i][j] += a[i] * b[j];
        }
    }
    for (int i = 0; i < 4; ++i) {
        int c = cb + cgl + i; int orow = orig_row(c);
        for (int j = 0; j < 4; ++j) {
            int k = kb + kgl + j;
            out[((k >> 2) * 2048 + c) * 4 + (k & 3)] = acc[i][j] + whh_d[orow * 512 + k];
        }
    }
}

__global__ void biasdc_k(const float* __restrict__ bih, const float* __restrict__ bhh,
                         const float* __restrict__ wih_d, const float* __restrict__ fc_b,
                         float* __restrict__ out) {
    int c = blockIdx.x * 256 + threadIdx.x;
    if (c >= 2048) return;
    int orow = orig_row(c);
    float s = bih[orow] + bhh[orow];
    for (int m = 0; m < 128; ++m) s += fc_b[m] * wih_d[orow * 128 + m];
    out[c] = s;
}

// ============================ LSTM path =====================================
__global__ __launch_bounds__(512)
void gx_kernel(const float* __restrict__ z, int zrstride,
               const float* __restrict__ wihP, const float* __restrict__ bih,
               const float* __restrict__ bhh, float* __restrict__ out) {
    int rg = blockIdx.x >> 2, cch = blockIdx.x & 3;
    int tid = threadIdx.x;
    __shared__ float zl[16 * 128];
    for (int i = tid; i < 2048; i += 512)
        zl[i] = z[(long)(rg * 16 + (i >> 7)) * zrstride + (i & 127)];
    __syncthreads();
    int c = cch * 512 + tid;
    int orow = orig_row(c);
    float bsum = bih[orow] + bhh[orow];
    float acc[16];
#pragma unroll
    for (int r = 0; r < 16; ++r) acc[r] = bsum;
    for (int m = 0; m < 128; ++m) {
        float wv = wihP[m * 2048 + c];
#pragma unroll
        for (int r = 0; r < 16; ++r) acc[r] += zl[r * 128 + m] * wv;
    }
    for (int r = 0; r < 16; ++r) out[(long)(rg * 16 + r) * 2048 + c] = acc[r];
}

__global__ __launch_bounds__(512)
void lstm_step(const float4* __restrict__ wh4, const float* __restrict__ gadd,
               int gstride, const float* __restrict__ h_in, float* __restrict__ h_out,
               float* __restrict__ cst, float* __restrict__ hall) {
    __shared__ float hs[8192];
    __shared__ float gb[16][32];
    int tid = threadIdx.x;
    float4* hs4 = (float4*)hs;
    const float4* hi4 = (const float4*)h_in;
#pragma unroll
    for (int i = 0; i < 4; ++i) hs4[tid + 512 * i] = hi4[tid + 512 * i];
    __syncthreads();
    int col = tid & 31, n = tid >> 5;
    int cg = blockIdx.x * 32 + col;
    float acc = gadd[n * gstride + cg];
    const float4* wp = wh4 + cg;
    const float4* hv = (const float4*)(hs + n * 512);
#pragma unroll 8
    for (int k4 = 0; k4 < 128; ++k4) {
        float4 wv = wp[(long)k4 * 2048];
        float4 h4 = hv[k4];
        acc += wv.x * h4.x + wv.y * h4.y + wv.z * h4.z + wv.w * h4.w;
    }
    gb[n][col] = acc;
    __syncthreads();
    if (col < 8) {
        int j = blockIdx.x * 8 + col;
        float gi = sig_(gb[n][col]);
        float gf = sig_(gb[n][col + 8]);
        float gg = tanhf(gb[n][col + 16]);
        float go = sig_(gb[n][col + 24]);
        int idx = n * 512 + j;
        float cv = gf * cst[idx] + gi * gg;
        cst[idx] = cv;
        float hvv = go * tanhf(cv);
        h_out[idx] = hvv;
        if (hall) hall[idx] = hvv;
    }
}

__global__ __launch_bounds__(512)
void fcmu_part(const float* __restrict__ x, const float* __restrict__ wP,
               float* __restrict__ part) {
    int rg = blockIdx.x >> 3, ks = blockIdx.x & 7;
    int tid = threadIdx.x;
    __shared__ float xl[16 * 512];
    for (int i = tid; i < 8192; i += 512)
        xl[i] = x[(long)(rg * 16 + (i >> 9)) * 4096 + ks * 512 + (i & 511)];
    __syncthreads();
    int j = tid & 127, rq = tid >> 7;
    float acc[4] = {0, 0, 0, 0};
    for (int k = 0; k < 512; ++k) {
        float wv = wP[(ks * 512 + k) * 128 + j];
#pragma unroll
        for (int i = 0; i < 4; ++i) acc[i] += xl[(rq + 4 * i) * 512 + k] * wv;
    }
    for (int i = 0; i < 4; ++i)
        part[((long)ks * 256 + rg * 16 + rq + 4 * i) * 128 + j] = acc[i];
}

__global__ void fcmu_red(const float* __restrict__ part, const float* __restrict__ b,
                         float* __restrict__ z) {
    int idx = blockIdx.x * 256 + threadIdx.x;  // 32768
    float s = b[idx & 127];
    for (int k = 0; k < 8; ++k) s += part[k * 32768 + idx];
    z[idx] = s;
}

__global__ __launch_bounds__(512)
void zs_k(const float* __restrict__ hall, const float* __restrict__ fcP,
          const float* __restrict__ fcb, float* __restrict__ zs) {
    int t = blockIdx.x;
    int tid = threadIdx.x;
    __shared__ float hs[8192];
    const float* h = hall + t * 8192;
    for (int i = tid; i < 8192; i += 512) hs[i] = h[i];
    __syncthreads();
    int j = tid & 127, ng = tid >> 7;
    float acc[4] = {0, 0, 0, 0};
    for (int k = 0; k < 512; ++k) {
        float wv = fcP[k * 128 + j];
#pragma unroll
        for (int i = 0; i < 4; ++i) acc[i] += hs[(ng + 4 * i) * 512 + k] * wv;
    }
    float bv = fcb[j];
    for (int i = 0; i < 4; ++i)
        zs[((ng + 4 * i) * 16 + t) * 128 + j] = acc[i] + bv;
}

__global__ __launch_bounds__(512)
void dfc_k(const float* __restrict__ zs, const float* __restrict__ dP,
           const float* __restrict__ db, float* __restrict__ out) {
    int rg = blockIdx.x >> 3, jc = blockIdx.x & 7;
    int tid = threadIdx.x;
    __shared__ float zl[16 * 128];
    for (int i = tid; i < 2048; i += 512) zl[i] = zs[(long)rg * 2048 + i];
    __syncthreads();
    int j = jc * 512 + tid;
    float acc[16];
#pragma unroll
    for (int r = 0; r < 16; ++r) acc[r] = 0.f;
    for (int m = 0; m < 128; ++m) {
        float wv = dP[(long)m * 4096 + j];
#pragma unroll
        for (int r = 0; r < 16; ++r) acc[r] += zl[r * 128 + m] * wv;
    }
    float bv = db[j];
    for (int r = 0; r < 16; ++r)
        out[(long)(rg * 16 + r) * 4096 + j] = fmaxf(acc[r] + bv, 0.f);
}

extern "C" void kernel_launch(void* const* d_in, const int* in_sizes, int n_in,
                              void* d_out, int out_size, void* d_ws, size_t ws_size,
                              hipStream_t stream) {
    (void)in_sizes; (void)n_in; (void)out_size; (void)ws_size;
    const float* video  = (const float*)d_in[0];
    const float* ec1_w  = (const float*)d_in[2];  const float* ec1_b = (const float*)d_in[3];
    const float* ec2_w  = (const float*)d_in[4];  const float* ec2_b = (const float*)d_in[5];
    const float* ec3_w  = (const float*)d_in[6];  const float* ec3_b = (const float*)d_in[7];
    const float* ec4_w  = (const float*)d_in[8];  const float* ec4_b = (const float*)d_in[9];
    const float* fcmu_w = (const float*)d_in[10]; const float* fcmu_b = (const float*)d_in[11];
    const float* dfc_w  = (const float*)d_in[12]; const float* dfc_b = (const float*)d_in[13];
    const float* dt1_w  = (const float*)d_in[14]; const float* dt1_b = (const float*)d_in[15];
    const float* dt2_w  = (const float*)d_in[16]; const float* dt2_b = (const float*)d_in[17];
    const float* dt3_w  = (const float*)d_in[18]; const float* dt3_b = (const float*)d_in[19];
    const float* dt4_w  = (const float*)d_in[20]; const float* dt4_b = (const float*)d_in[21];
    const float* wih_e  = (const float*)d_in[22]; const float* whh_e = (const float*)d_in[23];
    const float* bih_e  = (const float*)d_in[24]; const float* bhh_e = (const float*)d_in[25];
    const float* wih_d  = (const float*)d_in[26]; const float* whh_d = (const float*)d_in[27];
    const float* bih_d  = (const float*)d_in[28]; const float* bhh_d = (const float*)d_in[29];
    const float* fc_w   = (const float*)d_in[30]; const float* fc_b  = (const float*)d_in[31];

    float* ws = (float*)d_ws;
    // arenas (floats)
    float* A1 = ws;               // 8,388,608  ec1out -> [LSTM packs] -> dt3out
    float* A2 = ws + 8388608;     // 4,194,304  X0(video nhwc4) -> ec2out -> WT4 -> dt2out
    float* A3 = ws + 12582912;    // 2,097,152  ec3out -> dt1out
    float* A4 = ws + 14680064;    // 1,048,576  ec4out -> dfcout
    // A1-region packs (valid after ec2 completes)
    float* WH4_E  = A1;                 // 1,048,576 (reused for whh_d pack after enc chain)
    float* WH4_DC = A1 + 1048576;       // 1,048,576
    float* WIHP_E = A1 + 2097152;       // 262,144
    float* WIHP_D = A1 + 2359296;       // 262,144
    float* GX_E   = A1 + 2621440;       // 524,288
    float* GX_D0  = A1 + 3145728;       // 32,768
    float* BIASDC = A1 + 3178496;       // 2,048
    float* HA     = A1 + 3180544;       // 8,192
    float* HB     = A1 + 3188736;       // 8,192
    float* CB     = A1 + 3196928;       // 8,192
    float* HALL   = A1 + 3205120;       // 131,072
    float* FCMUP  = A1 + 3336192;       // 524,288
    float* ZPART  = A1 + 3860480;       // 262,144
    float* FCP    = A1 + 4122624;       // 65,536
    float* DFCP   = A1 + 4188160;       // 524,288
    float* DFCB   = A1 + 4712448;       // 4,096
    float* Z      = A1 + 4716544;       // 32,768
    float* ZS     = A1 + 4749312;       // 32,768
    float* WT3    = A1 + 4782080;       // 131,072  (ec3 table)
    float* WTd1   = A1 + 4913152;       // 524,288
    float* WTd2   = A1 + 5437440;       // 131,072
    float* WT4    = A2;                 // 524,288  (prepped after ec3, dead before dt2)
    // tail (persistent through whole call)
    float* WT1    = ws + 15728640;      // 2,048
    float* WT2    = ws + 15730688;      // 32,768
    float* WTd3   = ws + 15763456;      // 32,768
    float* WTd4   = ws + 15796224;      // 8,192
    float* DT4B   = ws + 15804416;      // 16
    float* X0     = A2;

    // ---- weight tables needed before A1 frees (tail) ----
    perm_w<3, 4, 32, 32><<<8, 256, 0, stream>>>(ec1_w, WT1);
    perm_w<32, 32, 64, 64><<<128, 256, 0, stream>>>(ec2_w, WT2);
    perm_w<64, 64, 32, 32><<<128, 256, 0, stream>>>(dt3_w, WTd3);
    perm_w<32, 32, 3, 16><<<32, 256, 0, stream>>>(dt4_w, WTd4);
    pad_b16<<<1, 64, 0, stream>>>(dt4_b, DT4B);

    // ---- encoder ----
    to_nhwc4<<<16384, 256, 0, stream>>>(video, X0);
    conv_gemm<4, 64, 64, 32, 128, 32, 4, 4, 4><<<2048, 256, 0, stream>>>(X0, WT1, ec1_b, A1);
    conv_gemm<32, 32, 32, 64, 128, 64, 4, 8, 16><<<512, 256, 0, stream>>>(A1, WT2, ec2_b, A2);

    // ---- A1 now free: all remaining prep ----
    perm_w<64, 64, 128, 128><<<512, 256, 0, stream>>>(ec3_w, WT3);
    perm_w<256, 256, 128, 128><<<2048, 256, 0, stream>>>(dt1_w, WTd1);
    perm_w<128, 128, 64, 64><<<512, 256, 0, stream>>>(dt2_w, WTd2);
    perm_fcmu<<<2048, 256, 0, stream>>>(fcmu_w, FCMUP);
    perm_dfc<<<2048, 256, 0, stream>>>(dfc_w, dfc_b, DFCP, DFCB);
    transp<<<256, 256, 0, stream>>>(fc_w, FCP, 128, 512);
    perm_wih<<<1024, 256, 0, stream>>>(wih_e, WIHP_E);
    perm_wih<<<1024, 256, 0, stream>>>(wih_d, WIHP_D);
    pack_whh<<<1024, 256, 0, stream>>>(whh_e, (float4*)WH4_E);
    merge_dc<<<256, 256, 0, stream>>>(wih_d, fc_w, whh_d, WH4_DC);
    biasdc_k<<<8, 256, 0, stream>>>(bih_d, bhh_d, wih_d, fc_b, BIASDC);
    hipMemsetAsync(HA, 0, 3 * 8192 * sizeof(float), stream);

    conv_gemm<64, 16, 16, 128, 128, 32, 4, 4, 16><<<512, 256, 0, stream>>>(A2, WT3, ec3_b, A3);
    perm_w<128, 128, 256, 256><<<2048, 256, 0, stream>>>(ec4_w, WT4);
    conv_gemm<128, 8, 8, 256, 64, 32, 4, 2, 32><<<512, 256, 0, stream>>>(A3, WT4, ec4_b, A4);

    // ---- fcmu -> Z ----
    fcmu_part<<<128, 512, 0, stream>>>(A4, FCMUP, ZPART);
    fcmu_red<<<128, 256, 0, stream>>>(ZPART, fcmu_b, Z);

    // ---- x projections ----
    gx_kernel<<<64, 512, 0, stream>>>(Z, 128, WIHP_E, bih_e, bhh_e, GX_E);
    gx_kernel<<<4, 512, 0, stream>>>(Z + 15 * 128, 2048, WIHP_D, bih_d, bhh_d, GX_D0);

    // ---- LSTM chains ----
    float* hin = HA; float* hout = HB;
    for (int t = 0; t < 16; ++t) {
        lstm_step<<<64, 512, 0, stream>>>((const float4*)WH4_E, GX_E + t * 2048, 32768,
                                          hin, hout, CB, (float*)nullptr);
        float* tmp = hin; hin = hout; hout = tmp;
    }
    pack_whh<<<1024, 256, 0, stream>>>(whh_d, (float4*)WH4_E);  // reuse slot for dec step 0
    lstm_step<<<64, 512, 0, stream>>>((const float4*)WH4_E, GX_D0, 2048,
                                      hin, hout, CB, HALL);
    { float* tmp = hin; hin = hout; hout = tmp; }
    for (int t = 1; t < 16; ++t) {
        lstm_step<<<64, 512, 0, stream>>>((const float4*)WH4_DC, BIASDC, 0,
                                          hin, hout, CB, HALL + t * 8192);
        float* tmp = hin; hin = hout; hout = tmp;
    }
    zs_k<<<16, 512, 0, stream>>>(HALL, FCP, fc_b, ZS);

    // ---- decoder ----
    dfc_k<<<128, 512, 0, stream>>>(ZS, DFCP, DFCB, A4);
    convt_gemm<256, 4, 4, 128, 128, 64, 64, 4, 4, 16, 0, 0><<<512, 256, 0, stream>>>(A4, WTd1, dt1_b, A3);
    convt_gemm<128, 8, 8, 64, 64, 128, 64, 4, 8, 16, 0, 0><<<512, 256, 0, stream>>>(A3, WTd2, dt2_b, A2);
    convt_gemm<64, 16, 16, 32, 32, 256, 32, 8, 4, 16, 0, 0><<<1024, 256, 0, stream>>>(A2, WTd3, dt3_b, A1);
    convt_gemm<32, 32, 32, 16, 3, 256, 16, 8, 2, 16, 1, 1><<<4096, 256, 0, stream>>>(A1, WTd4, DT4B, (float*)d_out);
}